// Round 12
// baseline (481.088 us; speedup 1.0000x reference)
//
#include <hip/hip_runtime.h>
#include <hip/hip_bf16.h>

// Problem constants (fixed by setup_inputs)
#define B_  2
#define C_  256
#define H_  64
#define W_  128
#define N_  (H_ * W_)   // 8192
#define K_  32          // top-k
#define Q_  24          // per-stream register queue depth
#define CK2 48          // candidates per row handed to stage 2 (bf16-sorted)

typedef short  short8  __attribute__((ext_vector_type(8)));
typedef short  short4v __attribute__((ext_vector_type(4)));
typedef float  floatx4 __attribute__((ext_vector_type(4)));

__device__ __forceinline__ unsigned umin_(unsigned a, unsigned b) { return a < b ? a : b; }
__device__ __forceinline__ unsigned umax_(unsigned a, unsigned b) { return a > b ? a : b; }
__device__ __forceinline__ ushort f2bf(float v) {
    __hip_bfloat16 h = __float2bfloat16(v);   // RNE
    ushort u; __builtin_memcpy(&u, &h, 2); return u;
}
// hardware median-of-3 (valid as shift-insert because q[i] <= q[i-1])
__device__ __forceinline__ unsigned med3u(unsigned a, unsigned b, unsigned c) {
    unsigned d;
    asm("v_med3_u32 %0, %1, %2, %3" : "=v"(d) : "v"(a), "v"(b), "v"(c));
    return d;
}

// key: top-19 bits of fp32 (clamped >=0, monotone) | 13-bit m index
__device__ __forceinline__ unsigned packkey(float v, int m) {
    const float vc = v > 0.0f ? v : 0.0f;
    unsigned b; __builtin_memcpy(&b, &vc, 4);
    return (b & 0xFFFFE000u) | (unsigned)m;
}

// descending-sorted register queue insert via v_med3_u32
__device__ __forceinline__ void qinsert(unsigned (&q)[Q_], unsigned k) {
#pragma unroll
    for (int i = Q_ - 1; i > 0; --i)
        q[i] = med3u(q[i - 1], k, q[i]);
    q[0] = umax_(q[0], k);
}

#define CSWAP(a, b) { const unsigned _mx = umax_(a, b); \
                      const unsigned _mn = umin_(a, b); (a) = _mx; (b) = _mn; }

// ---------------------------------------------------------------------------
// Kernel 1: prep (vectorized). fp32 [B][C][N] -> f1Tf fp32 [B][N][C],
//           f2Tf fp32 [B][N][C], f2T bf16 [B][N][C]
// ---------------------------------------------------------------------------
__global__ void raft_prep_kernel(const float* __restrict__ f1,
                                 const float* __restrict__ f2,
                                 float* __restrict__ f1Tf,
                                 ushort* __restrict__ f2T,
                                 float* __restrict__ f2Tf) {
    __shared__ float tile[32][33];
    const int nt = blockIdx.x;
    const int ct = blockIdx.y;
    const int z  = blockIdx.z;          // b*2 + which
    const int b  = z >> 1;
    const float* __restrict__ src = (z & 1) ? f2 : f1;
    const int tid = threadIdx.x;

    {
        const int cl = tid >> 3;        // 0..31
        const int nx = tid & 7;         // 0..7 (x4 n)
        const float4 v = *(const float4*)(
            src + ((size_t)b * C_ + (ct * 32 + cl)) * N_ + (nt * 32 + nx * 4));
        tile[cl][nx * 4 + 0] = v.x;
        tile[cl][nx * 4 + 1] = v.y;
        tile[cl][nx * 4 + 2] = v.z;
        tile[cl][nx * 4 + 3] = v.w;
    }
    __syncthreads();
    {
        const int nl = tid >> 3;        // 0..31
        const int c4 = (tid & 7) * 4;   // 0,4,..28
        float4 v;
        v.x = tile[c4 + 0][nl];
        v.y = tile[c4 + 1][nl];
        v.z = tile[c4 + 2][nl];
        v.w = tile[c4 + 3][nl];
        const size_t o = ((size_t)b * N_ + (nt * 32 + nl)) * C_ + (ct * 32 + c4);
        if (z & 1) {
            *(float4*)(f2Tf + o) = v;
            short4v h;
            h[0] = (short)f2bf(v.x); h[1] = (short)f2bf(v.y);
            h[2] = (short)f2bf(v.z); h[3] = (short)f2bf(v.w);
            *(short4v*)(f2T + o) = h;
        } else {
            *(float4*)(f1Tf + o) = v;
        }
    }
}

// ---------------------------------------------------------------------------
// Kernel 2: stage-1 — direct-from-global S^T MFMA, NO LDS staging, NO K-loop
// barriers. Block = 4 waves; wave w owns m-quarter w (2048 m) for the block's
// 32 n-rows (2 af sets). bm[2][8] register double-buffer, loads issued one
// full step ahead. 16 streams/row x top-24 -> 16-way merge tail -> top-48.
// grid: 512 blocks (b = blk&1 so each XCD streams a single batch's f2T).
// ---------------------------------------------------------------------------
__launch_bounds__(256, 2)
__global__ void raft_stage1_kernel(const float* __restrict__ f1Tf,
                                   const ushort* __restrict__ f2T,
                                   ushort* __restrict__ cand) {
    __shared__ unsigned mg[32][16][Q_];   // 49,152 B (merge tail only)

    const int bid  = blockIdx.x;
    const int b    = bid & 1;                    // XCD-parity batch split
    const int n0   = (bid >> 1) * 32;
    const int tid  = threadIdx.x;
    const int w    = tid >> 6;                   // wave 0..3 -> m-quarter
    const int lane = tid & 63;
    const int p    = lane & 15;
    const int q4   = lane >> 4;
    const int mbase = w * 2048;

    // ---- f1 fragments (B-operand), 2 n-sets: fp32 -> bf16 RNE ----
    short8 af[2][8];
    #pragma unroll
    for (int ns = 0; ns < 2; ++ns) {
        const float* __restrict__ arow =
            f1Tf + ((size_t)b * N_ + n0 + ns * 16 + p) * C_;
        #pragma unroll
        for (int ks = 0; ks < 8; ++ks) {
            const float4 x = *(const float4*)(arow + ks * 32 + q4 * 8);
            const float4 y = *(const float4*)(arow + ks * 32 + q4 * 8 + 4);
            short8 t;
            t[0] = (short)f2bf(x.x); t[1] = (short)f2bf(x.y);
            t[2] = (short)f2bf(x.z); t[3] = (short)f2bf(x.w);
            t[4] = (short)f2bf(y.x); t[5] = (short)f2bf(y.y);
            t[6] = (short)f2bf(y.z); t[7] = (short)f2bf(y.w);
            af[ns][ks] = t;
        }
    }

    unsigned q[2][Q_];
    #pragma unroll
    for (int ns = 0; ns < 2; ++ns)
        #pragma unroll
        for (int i = 0; i < Q_; ++i) q[ns][i] = 0u;

    // f2 quarter for this wave, row-major [2048][256] bf16
    const ushort* __restrict__ Bb =
        f2T + (size_t)b * N_ * C_ + (size_t)mbase * C_;

    // ---- prologue: load half-tiles hs=0,1 (A-operand frags, 16B/lane) ----
    short8 bm[2][8];
    #pragma unroll
    for (int par = 0; par < 2; ++par)
        #pragma unroll
        for (int ks = 0; ks < 8; ++ks)
            bm[par][ks] = *(const short8*)(
                Bb + (size_t)(par * 16 + p) * C_ + ks * 32 + q4 * 8);

    // ---- main loop: 128 half-tiles (16 m each), no barriers ----
    for (int hs2 = 0; hs2 < 64; ++hs2) {
        #pragma unroll
        for (int par = 0; par < 2; ++par) {
            const int hs = hs2 * 2 + par;
            const int m0 = mbase + hs * 16;

            floatx4 acc[2];
            acc[0] = (floatx4){0.f, 0.f, 0.f, 0.f};
            acc[1] = (floatx4){0.f, 0.f, 0.f, 0.f};
            #pragma unroll
            for (int ks = 0; ks < 8; ++ks) {
                acc[0] = __builtin_amdgcn_mfma_f32_16x16x32_bf16(bm[par][ks], af[0][ks], acc[0], 0, 0, 0);
                acc[1] = __builtin_amdgcn_mfma_f32_16x16x32_bf16(bm[par][ks], af[1][ks], acc[1], 0, 0, 0);
            }

            // refill bm[par] for hs+2 (in flight across the filter below)
            if (hs2 < 63) {
                const ushort* __restrict__ src =
                    Bb + (size_t)(hs * 16 + 32 + p) * C_;
                #pragma unroll
                for (int ks = 0; ks < 8; ++ks)
                    bm[par][ks] = *(const short8*)(src + ks * 32 + q4 * 8);
            }

            // in-register filter: D col = n (lane p), row = m = q4*4 + reg
            #pragma unroll
            for (int ns = 0; ns < 2; ++ns) {
                const int mb = m0 + q4 * 4;
                unsigned k0 = packkey(acc[ns][0], mb + 0);
                unsigned k1 = packkey(acc[ns][1], mb + 1);
                unsigned k2 = packkey(acc[ns][2], mb + 2);
                unsigned k3 = packkey(acc[ns][3], mb + 3);
                CSWAP(k0, k1); CSWAP(k2, k3); CSWAP(k0, k2); CSWAP(k1, k3); CSWAP(k1, k2);
                qinsert(q[ns], k0);
                if (__any(k1 > q[ns][Q_ - 1])) {
                    qinsert(q[ns], k1);
                    if (__any(k2 > q[ns][Q_ - 1])) {
                        qinsert(q[ns], k2);
                        if (__any(k3 > q[ns][Q_ - 1])) qinsert(q[ns], k3);
                    }
                }
            }
        }
    }

    // ---- merge tail: 16 sorted-24 lists per row -> top-48 ----
    #pragma unroll
    for (int ns = 0; ns < 2; ++ns)
        #pragma unroll
        for (int t = 0; t < Q_; ++t)
            mg[ns * 16 + p][w * 4 + q4][t] = q[ns][t];
    __syncthreads();

    if (tid < 32) {
        const unsigned* __restrict__ L = &mg[tid][0][0];   // 16 x 24 contiguous
        unsigned head[16]; int nxt[16];
        #pragma unroll
        for (int k = 0; k < 16; ++k) { head[k] = L[k * Q_]; nxt[k] = 1; }
        ushort* __restrict__ myc = cand + ((size_t)(b * N_ + n0 + tid)) * CK2;
        for (int t = 0; t < 48; ++t) {
            unsigned mx = head[0];
            #pragma unroll
            for (int k = 1; k < 16; ++k) mx = umax_(mx, head[k]);
            myc[t] = (ushort)(mx & 0x1FFFu);
            #pragma unroll
            for (int k = 0; k < 16; ++k) {
                const bool take = (head[k] == mx);
                const int  ix   = nxt[k] < Q_ ? nxt[k] : Q_ - 1;
                const unsigned nv = (nxt[k] < Q_) ? L[k * Q_ + ix] : 0u;
                head[k] = take ? nv : head[k];
                nxt[k] += take;
            }
        }
    }
}

// ---------------------------------------------------------------------------
// Kernel 3: stage-2 — fp32 sequential-FMA re-rank of 48 candidates + epilogue
// (r10 version — measured faster than the pipelined variant)
// grid: B_*N_ = 16384 blocks, 64 threads
// ---------------------------------------------------------------------------
__launch_bounds__(64)
__global__ void raft_rerank_kernel(const float* __restrict__ f1Tf,  // [B][N][C]
                                   const float* __restrict__ f2Tf,  // [B][N][C]
                                   const ushort* __restrict__ cand, // [B*N][CK2]
                                   float* __restrict__ out) {
    __shared__ float  aS[C_];
    __shared__ float  cs[CK2];
    __shared__ ushort cmS[CK2];
    const int row = blockIdx.x;
    const int b   = row >> 13;
    const int n   = row & (N_ - 1);
    const int tid = threadIdx.x;       // 0..63

    if (tid < CK2) cmS[tid] = cand[(size_t)row * CK2 + tid];
    *(float4*)(&aS[tid * 4]) = *(const float4*)(f1Tf + ((size_t)b * N_ + n) * C_ + tid * 4);
    __syncthreads();

    // fp32 score, single accumulator, c ascending, strict FMA
    if (tid < CK2) {
        const int m = cmS[tid];
        const float* __restrict__ bRow = f2Tf + ((size_t)b * N_ + m) * C_;
        float acc = 0.0f;
        for (int c4 = 0; c4 < C_; c4 += 4) {
            const float4 b4 = *(const float4*)(bRow + c4);
            acc = fmaf(aS[c4 + 0], b4.x, acc);
            acc = fmaf(aS[c4 + 1], b4.y, acc);
            acc = fmaf(aS[c4 + 2], b4.z, acc);
            acc = fmaf(aS[c4 + 3], b4.w, acc);
        }
        cs[tid] = acc;
    }
    __syncthreads();

    const int y0 = n >> 7, x0 = n & 127;
    if (tid < CK2) {
        const float v = cs[tid];
        const int m = cmS[tid];
        int rank = 0;
        for (int j = 0; j < CK2; ++j) {
            const float vj = cs[j];
            rank += (vj > v) || ((vj == v) && (cmS[j] < m));
        }
        if (rank < K_) {
            const size_t posn = (size_t)rank * N_ + n;
            out[(size_t)b * (K_ * N_) + posn] = v * 0.0625f;   // /sqrt(256), exact
            const size_t c1b = (size_t)1572864 + (size_t)b * 2 * K_ * N_;
            out[c1b + posn]                     = (float)((m >> 7) - y0);
            out[c1b + (size_t)(K_ * N_) + posn] = (float)((m & 127) - x0);
        }
    }
    if (tid < K_) {
        const size_t posn = (size_t)tid * N_ + n;
        const size_t c0b = (size_t)524288 + (size_t)b * 2 * K_ * N_;
        out[c0b + posn]                     = (float)y0;
        out[c0b + (size_t)(K_ * N_) + posn] = (float)x0;
        out[(size_t)2621440 + (size_t)b * (K_ * N_) + posn] = (float)b;
    }
}

// ---------------------------------------------------------------------------
extern "C" void kernel_launch(void* const* d_in, const int* in_sizes, int n_in,
                              void* d_out, int out_size, void* d_ws, size_t ws_size,
                              hipStream_t stream) {
    const float* f1 = (const float*)d_in[0];   // [B][C][N] fp32
    const float* f2 = (const float*)d_in[1];

    float*  f1Tf = (float*)d_ws;                             // 16,777,216 B
    float*  f2Tf = f1Tf + (size_t)B_ * N_ * C_;              // 16,777,216 B
    ushort* f2T  = (ushort*)(f2Tf + (size_t)B_ * N_ * C_);   //  8,388,608 B
    ushort* cand = f2T + (size_t)B_ * N_ * C_;               //  1,572,864 B

    raft_prep_kernel<<<dim3(N_ / 32, C_ / 32, B_ * 2), dim3(256), 0, stream>>>(
        f1, f2, f1Tf, f2T, f2Tf);

    raft_stage1_kernel<<<dim3(512), dim3(256), 0, stream>>>(f1Tf, f2T, cand);

    raft_rerank_kernel<<<dim3(B_ * N_), dim3(64), 0, stream>>>(f1Tf, f2Tf, cand,
                                                               (float*)d_out);
}